// Round 2
// baseline (2363.162 us; speedup 1.0000x reference)
//
#include <hip/hip_runtime.h>

// GCN on 1M nodes / 16M edges, collapsed to scalar per-node features.
//
//   deg[c]  = sum_{e: col=c} ew[e] + 1 (self loop)
//   dis     = rsqrt(deg)
//   S1[c]   = dis[c] * (sum_e dis[row]*ew*x[row]) + dis[c]^2 * x[c]
//   g[c]    = sum_j relu(S1[c]*W1[j] + b1[j]) * W2[j]
//   S2[c]   = dis[c] * (sum_e dis[row]*ew*g[row]) + dis[c]^2 * g[c]
//   y[c]    = sigmoid((S2[c]+b2)*Wl + bl)
//
// NOTE: harness passes integer inputs as int32 (edge_index arrives as int*),
// NOT the reference's int64 — reading it as long long was round 1's crash.

constexpr int N_NODES = 1000000;
constexpr int N_EDGES = 16000000;

__global__ void k_deg(const int* __restrict__ col,
                      const float* __restrict__ ew,
                      float* __restrict__ deg) {
  int i = blockIdx.x * blockDim.x + threadIdx.x;
  int stride = gridDim.x * blockDim.x;
  for (int e = i; e < N_EDGES; e += stride) {
    atomicAdd(&deg[col[e]], ew[e]);
  }
}

__global__ void k_dis(float* __restrict__ a) {
  int i = blockIdx.x * blockDim.x + threadIdx.x;
  if (i < N_NODES) {
    float d = a[i] + 1.0f;  // self-loop weight 1.0 => deg >= 1 always
    a[i] = rsqrtf(d);
  }
}

// acc[col] += dis[row] * ew * src[row]   (dis[col] factored out, applied later)
__global__ void k_scatter(const int* __restrict__ row,
                          const int* __restrict__ col,
                          const float* __restrict__ ew,
                          const float* __restrict__ dis,
                          const float* __restrict__ src,
                          float* __restrict__ acc) {
  int i = blockIdx.x * blockDim.x + threadIdx.x;
  int stride = gridDim.x * blockDim.x;
  for (int e = i; e < N_EDGES; e += stride) {
    int r = row[e];
    int c = col[e];
    atomicAdd(&acc[c], dis[r] * ew[e] * src[r]);
  }
}

// s1g holds s1 on entry; overwritten with g.
__global__ void k_g(const float* __restrict__ dis,
                    const float* __restrict__ x,
                    float* __restrict__ s1g,
                    const float* __restrict__ W1,
                    const float* __restrict__ b1,
                    const float* __restrict__ W2) {
  int i = blockIdx.x * blockDim.x + threadIdx.x;
  if (i >= N_NODES) return;
  float d = dis[i];
  float s1 = d * s1g[i] + d * d * x[i];  // conv1 aggregation incl. self loop
  float g = 0.f;
#pragma unroll
  for (int j = 0; j < 4; ++j) {
    float h = fmaf(s1, W1[j], b1[j]);    // out1[i,j]
    g = fmaf(fmaxf(h, 0.f), W2[j], g);   // relu -> @W2
  }
  s1g[i] = g;
}

// s2out holds s2 on entry (accumulated by k_scatter); overwritten with y.
__global__ void k_out(const float* __restrict__ dis,
                      const float* __restrict__ g,
                      float* __restrict__ s2out,
                      const float* __restrict__ b2,
                      const float* __restrict__ Wl,
                      const float* __restrict__ bl) {
  int i = blockIdx.x * blockDim.x + threadIdx.x;
  if (i >= N_NODES) return;
  float d = dis[i];
  float agg2 = d * s2out[i] + d * d * g[i];         // conv2 aggregation
  float v = fmaf(agg2 + b2[0], Wl[0], bl[0]);       // head linear
  s2out[i] = 1.0f / (1.0f + expf(-v));              // sigmoid
}

extern "C" void kernel_launch(void* const* d_in, const int* in_sizes, int n_in,
                              void* d_out, int out_size, void* d_ws, size_t ws_size,
                              hipStream_t stream) {
  const float* x   = (const float*)d_in[0];
  const int* ei    = (const int*)d_in[1];   // int32! harness narrows int64
  const float* ew  = (const float*)d_in[2];
  const float* W1  = (const float*)d_in[3];
  const float* b1  = (const float*)d_in[4];
  const float* W2  = (const float*)d_in[5];
  const float* b2  = (const float*)d_in[6];
  const float* Wl  = (const float*)d_in[7];
  const float* bl  = (const float*)d_in[8];

  const int* row = ei;            // edge_index[0]
  const int* col = ei + N_EDGES;  // edge_index[1]

  float* A = (float*)d_ws;        // deg -> dis      (4 MB)
  float* B = A + N_NODES;         // s1  -> g        (4 MB)
  float* C = (float*)d_out;       // s2  -> y        (reuse output buffer)

  hipMemsetAsync(d_ws, 0, 2ull * N_NODES * sizeof(float), stream);
  hipMemsetAsync(d_out, 0, (size_t)N_NODES * sizeof(float), stream);

  dim3 blk(256);
  dim3 egrid(4096);                        // grid-stride over 16M edges
  dim3 ngrid((N_NODES + 255) / 256);

  k_deg<<<egrid, blk, 0, stream>>>(col, ew, A);
  k_dis<<<ngrid, blk, 0, stream>>>(A);
  k_scatter<<<egrid, blk, 0, stream>>>(row, col, ew, A, x, B);
  k_g<<<ngrid, blk, 0, stream>>>(A, x, B, W1, b1, W2);
  k_scatter<<<egrid, blk, 0, stream>>>(row, col, ew, A, B, C);
  k_out<<<ngrid, blk, 0, stream>>>(A, B, C, b2, Wl, bl);
}

// Round 3
// 838.556 us; speedup vs baseline: 2.8181x; 2.8181x over previous
//
#include <hip/hip_runtime.h>

// GCN on 1M nodes / 16M edges, collapsed to scalar per-node features.
//
//   deg[c]  = sum_{e: col=c} ew[e] + 1 (self loop)
//   dis     = rsqrt(deg)
//   S1[c]   = dis[c] * (sum_e dis[row]*ew*x[row]) + dis[c]^2 * x[c]
//   g[c]    = sum_j relu(S1[c]*W1[j] + b1[j]) * W2[j]
//   S2[c]   = dis[c] * (sum_e dis[row]*ew*g[row]) + dis[c]^2 * g[c]
//   y[c]    = sigmoid((S2[c]+b2)*Wl + bl)
//
// R2 post-mortem: all three edge passes were bound by ~21 G random global
// fp32 atomics/s (k_deg ~= k_scatter duration despite 1/3 the gathers).
// R3: bucket edges by col>>12 once (count/scan/fill, 8B records), then each
// accumulation is per-bucket LDS accumulation with NO global atomics.

constexpr int N_NODES = 1000000;
constexpr int N_EDGES = 16000000;

constexpr int BSHIFT = 12;                 // bucket = col >> 12
constexpr int BNODES = 1 << BSHIFT;        // 4096 nodes per bucket
constexpr int NB = (N_NODES + BNODES - 1) / BNODES;  // 245
constexpr int NBLK = 2048;                 // partition blocks for count/fill
constexpr int CHUNK = (N_EDGES + NBLK - 1) / NBLK;   // 7813

// ---------------- bucketed path ----------------

__global__ void k_count(const int* __restrict__ col, unsigned* __restrict__ hist) {
  __shared__ unsigned cnt[NB];
  for (int i = threadIdx.x; i < NB; i += blockDim.x) cnt[i] = 0;
  __syncthreads();
  int blk = blockIdx.x;
  int e0 = blk * CHUNK, e1 = min(e0 + CHUNK, N_EDGES);
  for (int e = e0 + threadIdx.x; e < e1; e += blockDim.x)
    atomicAdd(&cnt[col[e] >> BSHIFT], 1u);
  __syncthreads();
  for (int i = threadIdx.x; i < NB; i += blockDim.x)
    hist[(size_t)i * NBLK + blk] = cnt[i];   // layout [NB][NBLK]
}

// One block, 256 threads. Turns hist[b][blk] counts into per-(bucket,block)
// start offsets; writes bucket bases to bbase[0..NB] (bbase[NB] = N_EDGES).
__global__ void k_scan(unsigned* __restrict__ hist, unsigned* __restrict__ bbase) {
  __shared__ unsigned sc[256];
  int b = threadIdx.x;
  unsigned s = 0;
  if (b < NB)
    for (int j = 0; j < NBLK; ++j) s += hist[(size_t)b * NBLK + j];
  sc[b] = s;
  __syncthreads();
  for (int d = 1; d < 256; d <<= 1) {   // Hillis-Steele inclusive scan
    unsigned v = (b >= d) ? sc[b - d] : 0;
    __syncthreads();
    sc[b] += v;
    __syncthreads();
  }
  unsigned base = sc[b] - s;            // exclusive
  if (b < NB) {
    bbase[b] = base;
    unsigned run = base;
    for (int j = 0; j < NBLK; ++j) {
      unsigned c = hist[(size_t)b * NBLK + j];
      hist[(size_t)b * NBLK + j] = run;
      run += c;
    }
    if (b == NB - 1) bbase[NB] = run;   // == N_EDGES
  }
}

// Re-read the same chunk as k_count; write 8B records grouped by bucket.
// record = (row<<12 | col&0xFFF, bits(ew));  row < 2^20 so this fits u32.
__global__ void k_fill(const int* __restrict__ row, const int* __restrict__ col,
                       const float* __restrict__ ew,
                       const unsigned* __restrict__ hist, uint2* __restrict__ rec) {
  __shared__ unsigned tail[NB];
  int blk = blockIdx.x;
  for (int i = threadIdx.x; i < NB; i += blockDim.x)
    tail[i] = hist[(size_t)i * NBLK + blk];
  __syncthreads();
  int e0 = blk * CHUNK, e1 = min(e0 + CHUNK, N_EDGES);
  for (int e = e0 + threadIdx.x; e < e1; e += blockDim.x) {
    int c = col[e];
    int b = c >> BSHIFT;
    unsigned slot = atomicAdd(&tail[b], 1u);   // LDS atomic
    unsigned packed = ((unsigned)row[e] << BSHIFT) | (unsigned)(c & (BNODES - 1));
    rec[slot] = make_uint2(packed, __float_as_uint(ew[e]));
  }
}

// One block per bucket: LDS accumulator over the bucket's 4096 nodes.
// mode 0: val = ew (degree).  mode 1: val = ew * p[row].
// Results are RAW segment sums (self-loop handled in node kernels).
__global__ __launch_bounds__(1024) void k_acc(const uint2* __restrict__ rec,
                                              const unsigned* __restrict__ bbase,
                                              const float* __restrict__ p,
                                              float* __restrict__ out, int mode) {
  __shared__ float acc[BNODES];
  for (int i = threadIdx.x; i < BNODES; i += blockDim.x) acc[i] = 0.f;
  __syncthreads();
  int b = blockIdx.x;
  unsigned s = bbase[b], e = bbase[b + 1];
  unsigned i = s + threadIdx.x;
  // 4-wide manual unroll: independent gathers in flight (latency hiding)
  for (; i + 3u * 1024u < e; i += 4u * 1024u) {
    uint2 r0 = rec[i], r1 = rec[i + 1024], r2 = rec[i + 2048], r3 = rec[i + 3072];
    float v0 = __uint_as_float(r0.y), v1 = __uint_as_float(r1.y);
    float v2 = __uint_as_float(r2.y), v3 = __uint_as_float(r3.y);
    if (mode) {
      v0 *= p[r0.x >> BSHIFT]; v1 *= p[r1.x >> BSHIFT];
      v2 *= p[r2.x >> BSHIFT]; v3 *= p[r3.x >> BSHIFT];
    }
    atomicAdd(&acc[r0.x & (BNODES - 1)], v0);
    atomicAdd(&acc[r1.x & (BNODES - 1)], v1);
    atomicAdd(&acc[r2.x & (BNODES - 1)], v2);
    atomicAdd(&acc[r3.x & (BNODES - 1)], v3);
  }
  for (; i < e; i += 1024) {
    uint2 r = rec[i];
    float v = __uint_as_float(r.y);
    if (mode) v *= p[r.x >> BSHIFT];
    atomicAdd(&acc[r.x & (BNODES - 1)], v);
  }
  __syncthreads();
  int base = b * BNODES;
  for (int j = threadIdx.x; j < BNODES && base + j < N_NODES; j += blockDim.x)
    out[base + j] = acc[j];
}

// A holds raw weighted degree on entry -> dis; P = dis*x.
__global__ void k_dis_p(const float* __restrict__ x, float* __restrict__ A,
                        float* __restrict__ P) {
  int i = blockIdx.x * blockDim.x + threadIdx.x;
  if (i < N_NODES) {
    float d = rsqrtf(A[i] + 1.0f);   // +1 self loop; always > 0
    A[i] = d;
    P[i] = d * x[i];
  }
}

// S holds raw s1 sums; compute g (store G) and q = dis*g (store into P).
__global__ void k_g2(const float* __restrict__ A, const float* __restrict__ x,
                     const float* __restrict__ S, float* __restrict__ G,
                     float* __restrict__ P, const float* __restrict__ W1,
                     const float* __restrict__ b1, const float* __restrict__ W2) {
  int i = blockIdx.x * blockDim.x + threadIdx.x;
  if (i >= N_NODES) return;
  float d = A[i];
  float s1 = d * S[i] + d * d * x[i];   // conv1 aggregation incl. self loop
  float g = 0.f;
#pragma unroll
  for (int j = 0; j < 4; ++j) {
    float h = fmaf(s1, W1[j], b1[j]);
    g = fmaf(fmaxf(h, 0.f), W2[j], g);
  }
  G[i] = g;
  P[i] = d * g;
}

__global__ void k_out2(const float* __restrict__ A, const float* __restrict__ G,
                       const float* __restrict__ S, const float* __restrict__ b2,
                       const float* __restrict__ Wl, const float* __restrict__ bl,
                       float* __restrict__ y) {
  int i = blockIdx.x * blockDim.x + threadIdx.x;
  if (i >= N_NODES) return;
  float d = A[i];
  float agg2 = d * S[i] + d * d * G[i];
  float v = fmaf(agg2 + b2[0], Wl[0], bl[0]);
  y[i] = 1.0f / (1.0f + expf(-v));
}

// ---------------- fallback (round-2 atomic path, in case ws is small) ----------------

__global__ void f_deg(const int* __restrict__ col, const float* __restrict__ ew,
                      float* __restrict__ deg) {
  int i = blockIdx.x * blockDim.x + threadIdx.x;
  int stride = gridDim.x * blockDim.x;
  for (int e = i; e < N_EDGES; e += stride) atomicAdd(&deg[col[e]], ew[e]);
}
__global__ void f_dis(float* __restrict__ a) {
  int i = blockIdx.x * blockDim.x + threadIdx.x;
  if (i < N_NODES) a[i] = rsqrtf(a[i] + 1.0f);
}
__global__ void f_scatter(const int* __restrict__ row, const int* __restrict__ col,
                          const float* __restrict__ ew, const float* __restrict__ dis,
                          const float* __restrict__ src, float* __restrict__ acc) {
  int i = blockIdx.x * blockDim.x + threadIdx.x;
  int stride = gridDim.x * blockDim.x;
  for (int e = i; e < N_EDGES; e += stride) {
    int r = row[e]; int c = col[e];
    atomicAdd(&acc[c], dis[r] * ew[e] * src[r]);
  }
}
__global__ void f_g(const float* __restrict__ dis, const float* __restrict__ x,
                    float* __restrict__ s1g, const float* __restrict__ W1,
                    const float* __restrict__ b1, const float* __restrict__ W2) {
  int i = blockIdx.x * blockDim.x + threadIdx.x;
  if (i >= N_NODES) return;
  float d = dis[i];
  float s1 = d * s1g[i] + d * d * x[i];
  float g = 0.f;
#pragma unroll
  for (int j = 0; j < 4; ++j) {
    float h = fmaf(s1, W1[j], b1[j]);
    g = fmaf(fmaxf(h, 0.f), W2[j], g);
  }
  s1g[i] = g;
}
__global__ void f_out(const float* __restrict__ dis, const float* __restrict__ g,
                      float* __restrict__ s2out, const float* __restrict__ b2,
                      const float* __restrict__ Wl, const float* __restrict__ bl) {
  int i = blockIdx.x * blockDim.x + threadIdx.x;
  if (i >= N_NODES) return;
  float d = dis[i];
  float agg2 = d * s2out[i] + d * d * g[i];
  float v = fmaf(agg2 + b2[0], Wl[0], bl[0]);
  s2out[i] = 1.0f / (1.0f + expf(-v));
}

// ---------------- launch ----------------

extern "C" void kernel_launch(void* const* d_in, const int* in_sizes, int n_in,
                              void* d_out, int out_size, void* d_ws, size_t ws_size,
                              hipStream_t stream) {
  const float* x  = (const float*)d_in[0];
  const int* ei   = (const int*)d_in[1];   // int32 (harness narrows int64)
  const float* ew = (const float*)d_in[2];
  const float* W1 = (const float*)d_in[3];
  const float* b1 = (const float*)d_in[4];
  const float* W2 = (const float*)d_in[5];
  const float* b2 = (const float*)d_in[6];
  const float* Wl = (const float*)d_in[7];
  const float* bl = (const float*)d_in[8];

  const int* row = ei;
  const int* col = ei + N_EDGES;

  const size_t REC_B  = (size_t)N_EDGES * 8;                 // 134,217,728
  const size_t NODE_B = (size_t)N_NODES * 4;                 // 4,000,000
  const size_t HIST_B = (size_t)NB * NBLK * 4;               // 2,007,040
  const size_t REQ = REC_B + 4 * NODE_B + HIST_B + (NB + 1) * 4;

  dim3 blk(256);
  dim3 ngrid((N_NODES + 255) / 256);

  if (ws_size >= REQ) {
    char* w = (char*)d_ws;
    uint2* rec      = (uint2*)w;
    float* A        = (float*)(w + REC_B);            // deg -> dis
    float* P        = A + N_NODES;                    // p = dis*x, then q = dis*g
    float* S        = P + N_NODES;                    // raw s1, then raw s2
    float* G        = S + N_NODES;                    // g
    unsigned* hist  = (unsigned*)(w + REC_B + 4 * NODE_B);
    unsigned* bbase = hist + (size_t)NB * NBLK;

    k_count<<<NBLK, blk, 0, stream>>>(col, hist);
    k_scan <<<1, 256, 0, stream>>>(hist, bbase);
    k_fill <<<NBLK, blk, 0, stream>>>(row, col, ew, hist, rec);
    k_acc  <<<NB, 1024, 0, stream>>>(rec, bbase, nullptr, A, 0);  // weighted degree
    k_dis_p<<<ngrid, blk, 0, stream>>>(x, A, P);
    k_acc  <<<NB, 1024, 0, stream>>>(rec, bbase, P, S, 1);        // raw s1
    k_g2   <<<ngrid, blk, 0, stream>>>(A, x, S, G, P, W1, b1, W2);
    k_acc  <<<NB, 1024, 0, stream>>>(rec, bbase, P, S, 1);        // raw s2
    k_out2 <<<ngrid, blk, 0, stream>>>(A, G, S, b2, Wl, bl, (float*)d_out);
  } else {
    // round-2 fallback: global-atomic path (needs only 8 MB ws)
    float* A = (float*)d_ws;
    float* B = A + N_NODES;
    float* C = (float*)d_out;
    hipMemsetAsync(d_ws, 0, 2ull * NODE_B, stream);
    hipMemsetAsync(d_out, 0, NODE_B, stream);
    dim3 egrid(4096);
    f_deg<<<egrid, blk, 0, stream>>>(col, ew, A);
    f_dis<<<ngrid, blk, 0, stream>>>(A);
    f_scatter<<<egrid, blk, 0, stream>>>(row, col, ew, A, x, B);
    f_g<<<ngrid, blk, 0, stream>>>(A, x, B, W1, b1, W2);
    f_scatter<<<egrid, blk, 0, stream>>>(row, col, ew, A, B, C);
    f_out<<<ngrid, blk, 0, stream>>>(A, B, C, b2, Wl, bl);
  }
}

// Round 4
// 452.738 us; speedup vs baseline: 5.2197x; 1.8522x over previous
//
#include <hip/hip_runtime.h>

// GCN on 1M nodes / 16M edges, collapsed to scalar per-node features.
//
//   deg[c]  = sum_{e: col=c} ew[e] + 1 (self loop)
//   dis     = rsqrt(deg)
//   S1[c]   = dis[c] * (sum_e dis[row]*ew*x[row]) + dis[c]^2 * x[c]
//   g[c]    = sum_j relu(S1[c]*W1[j] + b1[j]) * W2[j]
//   S2[c]   = dis[c] * (sum_e dis[row]*ew*g[row]) + dis[c]^2 * g[c]
//   y[c]    = sigmoid((S2[c]+b2)*Wl + bl)
//
// R3 post-mortem: k_fill scatter-writes amplified 3.2x (414MB for 128MB rec),
// single-block scan serial, k_acc only 16 waves/CU with ILP=4.
// R4: staged coalesced fill, flat parallel scan, k_acc unroll-8 + 2-way split.

constexpr int N_NODES = 1000000;
constexpr int N_EDGES = 16000000;

constexpr int BSHIFT = 12;
constexpr int BNODES = 1 << BSHIFT;                    // 4096 nodes/bucket
constexpr int NB = (N_NODES + BNODES - 1) / BNODES;    // 245 buckets
constexpr int EPT = 12;                                // edges/thread in count+fill
constexpr int FBLK = 256;                              // threads in count+fill
constexpr int CHUNK = FBLK * EPT;                      // 3072 edges/block
constexpr int NBLK = (N_EDGES + CHUNK - 1) / CHUNK;    // 5209 blocks
constexpr int NHIST = NB * NBLK;                       // 1,276,205
constexpr int SCAN_TPB = 256;
constexpr int SCAN_EPB = 1024;                         // 4 elems/thread
constexpr int NSCAN = (NHIST + SCAN_EPB - 1) / SCAN_EPB;  // 1247
constexpr int NHIST_PAD = NSCAN * SCAN_EPB;            // 1,276,928

// ---------------- build: count / scan / fill ----------------

__global__ __launch_bounds__(FBLK) void k_count(const int* __restrict__ col,
                                                unsigned* __restrict__ hist) {
  __shared__ unsigned cnt[256];
  int t = threadIdx.x;
  cnt[t] = 0;  // 256 >= NB
  __syncthreads();
  int e0 = blockIdx.x * CHUNK;
#pragma unroll
  for (int k = 0; k < EPT; ++k) {
    int e = e0 + k * FBLK + t;
    if (e < N_EDGES) atomicAdd(&cnt[col[e] >> BSHIFT], 1u);
  }
  __syncthreads();
  if (t < NB) hist[(size_t)t * NBLK + blockIdx.x] = cnt[t];
}

// Flat exclusive scan of hist[NHIST] (bucket-major => values ARE the global
// (bucket,block) record offsets; hist[b*NBLK] is bucket b's base).
__global__ __launch_bounds__(SCAN_TPB) void k_scanA(unsigned* __restrict__ h,
                                                    unsigned* __restrict__ bsum) {
  __shared__ unsigned sc[SCAN_TPB];
  int t = threadIdx.x;
  size_t base = (size_t)blockIdx.x * SCAN_EPB + (size_t)t * 4;
  uint4 v = *(const uint4*)(h + base);
  unsigned s = v.x + v.y + v.z + v.w;
  sc[t] = s;
  __syncthreads();
  for (int d = 1; d < SCAN_TPB; d <<= 1) {
    unsigned u = (t >= d) ? sc[t - d] : 0;
    __syncthreads();
    sc[t] += u;
    __syncthreads();
  }
  unsigned ex = sc[t] - s;
  uint4 o;
  o.x = ex; o.y = ex + v.x; o.z = ex + v.x + v.y; o.w = ex + v.x + v.y + v.z;
  *(uint4*)(h + base) = o;
  if (t == SCAN_TPB - 1) bsum[blockIdx.x] = sc[t];
}

__global__ __launch_bounds__(1024) void k_scanB(unsigned* __restrict__ bsum) {
  __shared__ unsigned sc[1024];
  int t = threadIdx.x;
  unsigned a0 = (2 * t < NSCAN) ? bsum[2 * t] : 0;
  unsigned a1 = (2 * t + 1 < NSCAN) ? bsum[2 * t + 1] : 0;
  unsigned s = a0 + a1;
  sc[t] = s;
  __syncthreads();
  for (int d = 1; d < 1024; d <<= 1) {
    unsigned u = (t >= d) ? sc[t - d] : 0;
    __syncthreads();
    sc[t] += u;
    __syncthreads();
  }
  unsigned ex = sc[t] - s;
  if (2 * t < NSCAN) bsum[2 * t] = ex;
  if (2 * t + 1 < NSCAN) bsum[2 * t + 1] = ex + a0;
}

__global__ __launch_bounds__(SCAN_TPB) void k_scanC(unsigned* __restrict__ h,
                                                    const unsigned* __restrict__ bsum) {
  unsigned add = bsum[blockIdx.x];
  size_t base = (size_t)blockIdx.x * SCAN_EPB + (size_t)threadIdx.x * 4;
  uint4 v = *(uint4*)(h + base);
  v.x += add; v.y += add; v.z += add; v.w += add;
  *(uint4*)(h + base) = v;
}

// Register-stash + LDS-reorder fill: coalesced record writes.
// record = (row<<12 | col&0xFFF, bits(ew)); row < 2^20 fits.
__global__ __launch_bounds__(FBLK) void k_fill(const int* __restrict__ row,
                                               const int* __restrict__ col,
                                               const float* __restrict__ ew,
                                               const unsigned* __restrict__ hist,
                                               uint2* __restrict__ rec) {
  __shared__ unsigned lhist[256];
  __shared__ unsigned lb[256];
  __shared__ unsigned tail[256];
  __shared__ unsigned gbase[NB];
  __shared__ uint2 stage[CHUNK];
  __shared__ unsigned char sbkt[CHUNK];

  int t = threadIdx.x;
  int blk = blockIdx.x;
  lhist[t] = 0;
  for (int i = t; i < NB; i += FBLK) gbase[i] = hist[(size_t)i * NBLK + blk];
  __syncthreads();

  int e0 = blk * CHUNK;
  unsigned pk[EPT], wv[EPT];
  int bk[EPT];
#pragma unroll
  for (int k = 0; k < EPT; ++k) {
    int e = e0 + k * FBLK + t;
    bk[k] = -1;
    if (e < N_EDGES) {
      int c = col[e];
      pk[k] = ((unsigned)row[e] << BSHIFT) | (unsigned)(c & (BNODES - 1));
      wv[k] = __float_as_uint(ew[e]);
      bk[k] = c >> BSHIFT;
      atomicAdd(&lhist[bk[k]], 1u);
    }
  }
  __syncthreads();

  unsigned own = lhist[t];
  lb[t] = own;
  __syncthreads();
  for (int d = 1; d < 256; d <<= 1) {           // Hillis-Steele inclusive
    unsigned u = (t >= d) ? lb[t - d] : 0;
    __syncthreads();
    lb[t] += u;
    __syncthreads();
  }
  unsigned total = lb[255];
  unsigned ex = lb[t] - own;
  __syncthreads();
  lb[t] = ex;           // exclusive local offsets
  tail[t] = ex;
  __syncthreads();

#pragma unroll
  for (int k = 0; k < EPT; ++k) {
    if (bk[k] >= 0) {
      unsigned s = atomicAdd(&tail[bk[k]], 1u);
      stage[s] = make_uint2(pk[k], wv[k]);
      sbkt[s] = (unsigned char)bk[k];
    }
  }
  __syncthreads();

  // staged order is bucket-sorted: consecutive s -> consecutive global dest
  for (unsigned s = t; s < total; s += FBLK) {
    unsigned b = sbkt[s];
    rec[gbase[b] + (s - lb[b])] = stage[s];
  }
}

// ---------------- accumulate: one (bucket,part) per block ----------------
// mode 0: val = ew (weighted degree). mode 1: val = ew * p[row].
// out[part*N_NODES + node] gets the partial raw segment sum.
__global__ __launch_bounds__(1024) void k_acc(const uint2* __restrict__ rec,
                                              const unsigned* __restrict__ hist,
                                              const float* __restrict__ p,
                                              float* __restrict__ out,
                                              int mode, int split) {
  __shared__ float acc[BNODES];
  for (int i = threadIdx.x; i < BNODES; i += 1024) acc[i] = 0.f;
  __syncthreads();
  int b = blockIdx.x / split;
  int part = blockIdx.x - b * split;
  unsigned bs = hist[(size_t)b * NBLK];
  unsigned be = (b + 1 < NB) ? hist[(size_t)(b + 1) * NBLK] : (unsigned)N_EDGES;
  unsigned len = be - bs;
  unsigned s = bs + (unsigned)(((unsigned long long)len * part) / split);
  unsigned e = bs + (unsigned)(((unsigned long long)len * (part + 1)) / split);

  unsigned i = s + threadIdx.x;
  for (; i + 7u * 1024u < e; i += 8u * 1024u) {   // 8 gathers in flight
    uint2 r[8];
#pragma unroll
    for (int j = 0; j < 8; ++j) r[j] = rec[i + (unsigned)j * 1024u];
    float v[8];
#pragma unroll
    for (int j = 0; j < 8; ++j) {
      v[j] = __uint_as_float(r[j].y);
      if (mode) v[j] *= p[r[j].x >> BSHIFT];
    }
#pragma unroll
    for (int j = 0; j < 8; ++j)
      atomicAdd(&acc[r[j].x & (BNODES - 1)], v[j]);
  }
  for (; i < e; i += 1024u) {
    uint2 r = rec[i];
    float v = __uint_as_float(r.y);
    if (mode) v *= p[r.x >> BSHIFT];
    atomicAdd(&acc[r.x & (BNODES - 1)], v);
  }
  __syncthreads();

  float* o = out + (size_t)part * N_NODES;
  int base = b * BNODES;
  for (int j = threadIdx.x; j < BNODES && base + j < N_NODES; j += 1024)
    o[base + j] = acc[j];
}

// ---------------- node-wise kernels (merge partials for free) ----------------

__global__ void k_dis_p(const float* __restrict__ x, const float* __restrict__ Da,
                        const float* __restrict__ Db, float* __restrict__ A,
                        float* __restrict__ P, int split) {
  int i = blockIdx.x * blockDim.x + threadIdx.x;
  if (i >= N_NODES) return;
  float deg = Da[i] + (split > 1 ? Db[i] : 0.f) + 1.0f;  // +1 self loop
  float d = rsqrtf(deg);
  A[i] = d;
  P[i] = d * x[i];
}

// S1 raw in Da(+Db); writes P = dis*g (g recomputed later as P/A).
__global__ void k_g2(const float* __restrict__ A, const float* __restrict__ x,
                     const float* __restrict__ Da, const float* __restrict__ Db,
                     float* __restrict__ P, const float* __restrict__ W1,
                     const float* __restrict__ b1, const float* __restrict__ W2,
                     int split) {
  int i = blockIdx.x * blockDim.x + threadIdx.x;
  if (i >= N_NODES) return;
  float d = A[i];
  float sraw = Da[i] + (split > 1 ? Db[i] : 0.f);
  float s1 = d * sraw + d * d * x[i];
  float g = 0.f;
#pragma unroll
  for (int j = 0; j < 4; ++j) {
    float h = fmaf(s1, W1[j], b1[j]);
    g = fmaf(fmaxf(h, 0.f), W2[j], g);
  }
  P[i] = d * g;
}

__global__ void k_out2(const float* __restrict__ A, const float* __restrict__ P,
                       const float* __restrict__ Da, const float* __restrict__ Db,
                       const float* __restrict__ b2, const float* __restrict__ Wl,
                       const float* __restrict__ bl, float* __restrict__ y,
                       int split) {
  int i = blockIdx.x * blockDim.x + threadIdx.x;
  if (i >= N_NODES) return;
  float d = A[i];
  float g = P[i] / d;                                   // d in (0,1], safe
  float sraw = Da[i] + (split > 1 ? Db[i] : 0.f);
  float agg2 = d * sraw + d * d * g;
  float v = fmaf(agg2 + b2[0], Wl[0], bl[0]);
  y[i] = 1.0f / (1.0f + expf(-v));
}

// ---------------- fallback (round-2 global-atomic path) ----------------

__global__ void f_deg(const int* __restrict__ col, const float* __restrict__ ew,
                      float* __restrict__ deg) {
  int i = blockIdx.x * blockDim.x + threadIdx.x;
  int stride = gridDim.x * blockDim.x;
  for (int e = i; e < N_EDGES; e += stride) atomicAdd(&deg[col[e]], ew[e]);
}
__global__ void f_dis(float* __restrict__ a) {
  int i = blockIdx.x * blockDim.x + threadIdx.x;
  if (i < N_NODES) a[i] = rsqrtf(a[i] + 1.0f);
}
__global__ void f_scatter(const int* __restrict__ row, const int* __restrict__ col,
                          const float* __restrict__ ew, const float* __restrict__ dis,
                          const float* __restrict__ src, float* __restrict__ acc) {
  int i = blockIdx.x * blockDim.x + threadIdx.x;
  int stride = gridDim.x * blockDim.x;
  for (int e = i; e < N_EDGES; e += stride) {
    int r = row[e]; int c = col[e];
    atomicAdd(&acc[c], dis[r] * ew[e] * src[r]);
  }
}
__global__ void f_g(const float* __restrict__ dis, const float* __restrict__ x,
                    float* __restrict__ s1g, const float* __restrict__ W1,
                    const float* __restrict__ b1, const float* __restrict__ W2) {
  int i = blockIdx.x * blockDim.x + threadIdx.x;
  if (i >= N_NODES) return;
  float d = dis[i];
  float s1 = d * s1g[i] + d * d * x[i];
  float g = 0.f;
#pragma unroll
  for (int j = 0; j < 4; ++j) {
    float h = fmaf(s1, W1[j], b1[j]);
    g = fmaf(fmaxf(h, 0.f), W2[j], g);
  }
  s1g[i] = g;
}
__global__ void f_out(const float* __restrict__ dis, const float* __restrict__ g,
                      float* __restrict__ s2out, const float* __restrict__ b2,
                      const float* __restrict__ Wl, const float* __restrict__ bl) {
  int i = blockIdx.x * blockDim.x + threadIdx.x;
  if (i >= N_NODES) return;
  float d = dis[i];
  float agg2 = d * s2out[i] + d * d * g[i];
  float v = fmaf(agg2 + b2[0], Wl[0], bl[0]);
  s2out[i] = 1.0f / (1.0f + expf(-v));
}

// ---------------- launch ----------------

extern "C" void kernel_launch(void* const* d_in, const int* in_sizes, int n_in,
                              void* d_out, int out_size, void* d_ws, size_t ws_size,
                              hipStream_t stream) {
  const float* x  = (const float*)d_in[0];
  const int* ei   = (const int*)d_in[1];   // int32 (harness narrows int64)
  const float* ew = (const float*)d_in[2];
  const float* W1 = (const float*)d_in[3];
  const float* b1 = (const float*)d_in[4];
  const float* W2 = (const float*)d_in[5];
  const float* b2 = (const float*)d_in[6];
  const float* Wl = (const float*)d_in[7];
  const float* bl = (const float*)d_in[8];

  const int* row = ei;
  const int* col = ei + N_EDGES;

  const size_t REC_B  = (size_t)N_EDGES * 8;          // 134,217,728
  const size_t HIST_B = (size_t)NHIST_PAD * 4;        // 5,107,712
  const size_t BSUM_B = 4992;                         // NSCAN*4 rounded to 16
  const size_t NODE_B = (size_t)N_NODES * 4;          // 4,000,000
  const size_t REQ1 = REC_B + HIST_B + BSUM_B + 3 * NODE_B;  // Da, A, P
  const size_t REQ2 = REQ1 + NODE_B;                          // + Db

  dim3 blk(256);
  dim3 ngrid((N_NODES + 255) / 256);

  if (ws_size >= REQ1) {
    int split = (ws_size >= REQ2) ? 2 : 1;
    char* w = (char*)d_ws;
    uint2* rec      = (uint2*)w;
    unsigned* hist  = (unsigned*)(w + REC_B);
    unsigned* bsum  = (unsigned*)(w + REC_B + HIST_B);
    float* Da       = (float*)(w + REC_B + HIST_B + BSUM_B);
    float* A        = Da + (size_t)split * N_NODES;   // Db right after Da if split
    float* P        = A + N_NODES;
    float* Db       = (split > 1) ? (Da + N_NODES) : Da;

    k_count<<<NBLK, FBLK, 0, stream>>>(col, hist);
    k_scanA<<<NSCAN, SCAN_TPB, 0, stream>>>(hist, bsum);
    k_scanB<<<1, 1024, 0, stream>>>(bsum);
    k_scanC<<<NSCAN, SCAN_TPB, 0, stream>>>(hist, bsum);
    k_fill <<<NBLK, FBLK, 0, stream>>>(row, col, ew, hist, rec);

    k_acc  <<<NB * split, 1024, 0, stream>>>(rec, hist, nullptr, Da, 0, split);
    k_dis_p<<<ngrid, blk, 0, stream>>>(x, Da, Db, A, P, split);
    k_acc  <<<NB * split, 1024, 0, stream>>>(rec, hist, P, Da, 1, split);
    k_g2   <<<ngrid, blk, 0, stream>>>(A, x, Da, Db, P, W1, b1, W2, split);
    k_acc  <<<NB * split, 1024, 0, stream>>>(rec, hist, P, Da, 1, split);
    k_out2 <<<ngrid, blk, 0, stream>>>(A, P, Da, Db, b2, Wl, bl, (float*)d_out, split);
  } else {
    float* Aw = (float*)d_ws;
    float* Bw = Aw + N_NODES;
    float* Cw = (float*)d_out;
    hipMemsetAsync(d_ws, 0, 2ull * NODE_B, stream);
    hipMemsetAsync(d_out, 0, NODE_B, stream);
    dim3 egrid(4096);
    f_deg<<<egrid, blk, 0, stream>>>(col, ew, Aw);
    f_dis<<<ngrid, blk, 0, stream>>>(Aw);
    f_scatter<<<egrid, blk, 0, stream>>>(row, col, ew, Aw, x, Bw);
    f_g<<<ngrid, blk, 0, stream>>>(Aw, x, Bw, W1, b1, W2);
    f_scatter<<<egrid, blk, 0, stream>>>(row, col, ew, Aw, Bw, Cw);
    f_out<<<ngrid, blk, 0, stream>>>(Aw, Bw, Cw, b2, Wl, bl);
  }
}